// Round 19
// baseline (120.078 us; speedup 1.0000x reference)
//
#include <hip/hip_runtime.h>

#define NB 2
#define NT 2048
#define NC 1024
#define NH 16
#define ND 64
#define NC2 2048
// 1/sqrt(D) * log2(e): folded into q-GEMM epilogue; flash uses 2^s directly.
#define QSCALE (0.125f * 1.4426950408889634f)

typedef __attribute__((ext_vector_type(8))) __bf16 bf16x8;
typedef __attribute__((ext_vector_type(8))) unsigned short ushort8;
typedef __attribute__((ext_vector_type(4))) float f32x4;

__device__ __forceinline__ unsigned short bf16_bits(float f) {
  union { float f; unsigned int u; } x; x.f = f;
  unsigned int r = x.u + 0x7fffu + ((x.u >> 16) & 1u);
  return (unsigned short)(r >> 16);
}
__device__ __forceinline__ float bf2f(unsigned short u) {
  union { unsigned int u; float f; } x; x.u = ((unsigned int)u) << 16;
  return x.f;
}
__device__ __forceinline__ void g2l16(const void* g, void* l) {
  __builtin_amdgcn_global_load_lds(
      (const __attribute__((address_space(1))) unsigned int*)g,
      (__attribute__((address_space(3))) unsigned int*)l, 16, 0, 0);
}
__device__ __forceinline__ bf16x8 ld8(const unsigned short* p) {
  return *(const bf16x8*)p;
}
__device__ __forceinline__ unsigned int cvtpk(float lo, float hi) {
  unsigned int r;
  asm("v_cvt_pk_bf16_f32 %0, %1, %2" : "=v"(r) : "v"(lo), "v"(hi));
  return r;
}
__device__ __forceinline__ float vexp2(float x) {  // 2^x
  float r;
  asm("v_exp_f32 %0, %1" : "=v"(r) : "v"(x));
  return r;
}

// ---------- per-wave dtype self-detect: 1 if d_in[0] holds f32, 0 if bf16 ----
__device__ __forceinline__ int wave_is_f32(const unsigned short* __restrict__ x) {
  const int lane = threadIdx.x & 63;
  ulonglong2 v = ((const ulonglong2*)x)[lane];
  const unsigned short* u = (const unsigned short*)&v;
  int c = 0;
#pragma unroll
  for (int k = 0; k < 8; ++k) {
    int e = (u[k] >> 7) & 0xFF;
    c += (e != 0 && (e < 112 || e > 142)) ? 1 : 0;
  }
#pragma unroll
  for (int off = 32; off > 0; off >>= 1) c += __shfl_down(c, off);
  return __shfl(c, 0) > 64;
}

// ---------- fused prep: activation convert (f32 only) + weight transpose ----------
__global__ __launch_bounds__(256) void prep(const void* __restrict__ xq,
                                            const void* __restrict__ xkv,
                                            const void* __restrict__ w0,
                                            const void* __restrict__ w1,
                                            const void* __restrict__ w2,
                                            unsigned short* __restrict__ oq,
                                            unsigned short* __restrict__ okv,
                                            unsigned short* __restrict__ o0,
                                            unsigned short* __restrict__ o1,
                                            unsigned short* __restrict__ o2) {
  __shared__ unsigned short tile[32][33];
  const int bx = blockIdx.x, by = blockIdx.y;
  const int f = wave_is_f32((const unsigned short*)xq);
  if (bx < 128) {
    if (!f) return;  // bf16: consumers read d_in directly; no copy needed
    const int fb = bx * 32 + by;  // [0, 4096)
    const void* in = (fb < 2048) ? xq : xkv;
    unsigned short* out = (fb < 2048) ? oq : okv;
    const int i = (fb & 2047) * 256 + threadIdx.x;
    const float4* p = (const float4*)in;
    float4 a = p[i * 2], b = p[i * 2 + 1];
    ushort8 o;
    o[0] = bf16_bits(a.x); o[1] = bf16_bits(a.y); o[2] = bf16_bits(a.z); o[3] = bf16_bits(a.w);
    o[4] = bf16_bits(b.x); o[5] = bf16_bits(b.y); o[6] = bf16_bits(b.z); o[7] = bf16_bits(b.w);
    *(ushort8*)&out[(size_t)i * 8] = o;
  } else {
    const int tb = bx - 128;
    const void* in; unsigned short* out; int cols, cb;
    if (tb < 32)      { in = w0; out = o0; cols = NC;  cb = tb; }
    else if (tb < 96) { in = w1; out = o1; cols = NC2; cb = tb - 32; }
    else              { in = w2; out = o2; cols = NC;  cb = tb - 96; }
    const int c0 = cb * 32, r0 = by * 32;  // rows = NC for all
    const int tx = threadIdx.x & 31, ty = threadIdx.x >> 5;
#pragma unroll
    for (int i = 0; i < 32; i += 8) {
      size_t idx = (size_t)(r0 + ty + i) * cols + c0 + tx;
      tile[ty + i][tx] = f ? bf16_bits(((const float*)in)[idx]) : ((const unsigned short*)in)[idx];
    }
    __syncthreads();
#pragma unroll
    for (int i = 0; i < 32; i += 8)
      out[(size_t)(c0 + ty + i) * NC + r0 + tx] = tile[tx][ty + i];
  }
}

// ---------- qkv projection GEMM: 256x256 tile, 8 waves, 4-phase pipelined ----------
// (r15-verified: T2 st_16x32 swizzle + 4-phase interleave + counted tile-end
// drain + setprio; panels by: 0-3 q, 4-7 K frag-major, 8-11 V frag-major.)
__global__ __launch_bounds__(512) void gemm_qkv256(const unsigned short* __restrict__ xq_raw,
                                                   const unsigned short* __restrict__ xkv_raw,
                                                   const unsigned short* __restrict__ xq_cvt,
                                                   const unsigned short* __restrict__ xkv_cvt,
                                                   const unsigned short* __restrict__ Wqt,
                                                   const unsigned short* __restrict__ Wkvt,
                                                   const void* __restrict__ bq,
                                                   const void* __restrict__ bkv,
                                                   unsigned short* __restrict__ qb,
                                                   unsigned short* __restrict__ kf2,
                                                   unsigned short* __restrict__ vt2) {
  extern __shared__ char smem[];  // 131072 B
  const int f = wave_is_f32(xq_raw);
  const int bx = blockIdx.x, by = blockIdx.y;
  const bool isq = by < 4;
  const unsigned short* A  = isq ? (f ? xq_cvt : xq_raw) : (f ? xkv_cvt : xkv_raw);
  const unsigned short* Bt = isq ? Wqt : Wkvt;
  const int m0 = bx * 256;
  const int n0 = (isq ? by : by - 4) * 256;
  const int tid = threadIdx.x, w = tid >> 6, lane = tid & 63;
  const int lq = lane & 15, lhi = lane >> 4;
  const int wr = w >> 2, wc = w & 3;
  f32x4 acc[8][4] = {};

#define STAGE_HALF(kt_, bf_, sel_)                                                   \
  {                                                                                  \
    const unsigned short* G_ = ((sel_) < 2) ? A : Bt;                                \
    const int r0_ = ((sel_) < 2) ? m0 : n0;                                          \
    const int h_ = (sel_) & 1;                                                       \
    char* db_ = smem + (bf_)*65536 + ((sel_) >> 1) * 32768 + h_ * 16384;             \
    _Pragma("unroll") for (int q_ = 0; q_ < 2; ++q_) {                               \
      const int o_ = w * 1024 + lane * 16 + q_ * 8192;                               \
      const int os_ = o_ ^ (((o_ >> 9) & 1) << 5);                                   \
      g2l16((const char*)G_ +                                                        \
                ((size_t)(r0_ + h_ * 128 + (os_ >> 7)) * NC + (kt_)*64) * 2 +        \
                (os_ & 127),                                                         \
            db_ + w * 1024 + q_ * 8192);                                             \
    }                                                                                \
  }

  STAGE_HALF(0, 0, 0);
  STAGE_HALF(0, 0, 1);
  STAGE_HALF(0, 0, 2);
  STAGE_HALF(0, 0, 3);
  asm volatile("s_waitcnt vmcnt(0)");
  __builtin_amdgcn_sched_barrier(0);
  __builtin_amdgcn_s_barrier();

  for (int T = 0; T < 16; ++T) {
    const int c = T & 1;
    const char* Ah = smem + c * 65536 + wr * 16384;
    const char* Bh = smem + c * 65536 + 32768 + (wc >> 1) * 16384;
    const int brh = (wc & 1) * 64;
    bf16x8 bF[2][4];
#pragma unroll
    for (int ph = 0; ph < 4; ++ph) {
      if (ph == 0) {
#pragma unroll
        for (int kk = 0; kk < 2; ++kk)
#pragma unroll
          for (int fj = 0; fj < 4; ++fj) {
            const int rowh = brh + fj * 16 + lq;
            const int o = rowh * 128 + kk * 64 + lhi * 16;
            bF[kk][fj] = ld8((const unsigned short*)(Bh + (o ^ (((o >> 9) & 1) << 5))));
          }
      }
      bf16x8 aF[2][2];
#pragma unroll
      for (int kk = 0; kk < 2; ++kk)
#pragma unroll
        for (int ii = 0; ii < 2; ++ii) {
          const int rowh = (ph * 2 + ii) * 16 + lq;
          const int o = rowh * 128 + kk * 64 + lhi * 16;
          aF[kk][ii] = ld8((const unsigned short*)(Ah + (o ^ (((o >> 9) & 1) << 5))));
        }
      if (T < 15) STAGE_HALF(T + 1, c ^ 1, ph);
      __builtin_amdgcn_s_barrier();
      __builtin_amdgcn_s_setprio(1);
#pragma unroll
      for (int kk = 0; kk < 2; ++kk)
#pragma unroll
        for (int ii = 0; ii < 2; ++ii)
#pragma unroll
          for (int fj = 0; fj < 4; ++fj)
            acc[ph * 2 + ii][fj] =
                __builtin_amdgcn_mfma_f32_16x16x32_bf16(aF[kk][ii], bF[kk][fj],
                                                        acc[ph * 2 + ii][fj], 0, 0, 0);
      __builtin_amdgcn_s_setprio(0);
    }
    asm volatile("s_waitcnt vmcnt(0)");
    __builtin_amdgcn_sched_barrier(0);
    __builtin_amdgcn_s_barrier();
  }
#undef STAGE_HALF

  // ---- epilogue (buffers all consumed; reuse smem for wave-private relayout) ----
  const void* bias = isq ? bq : bkv;
  const int rowbase = m0 + wr * 128;
  unsigned short* Cw = (unsigned short*)(smem + w * 2304);  // 16x72 elems per wave
  if (by >= 8) {
    const int n0v = (by - 8) * 256;
#pragma unroll
    for (int fj = 0; fj < 4; ++fj) {
      const int cv = n0v + wc * 64 + fj * 16 + lq;
      const float bj = f ? ((const float*)bias)[NC + cv]
                         : bf2f(((const unsigned short*)bias)[NC + cv]);
      const int hV = cv >> 6, dcol = cv & 63;
#pragma unroll
      for (int fi = 0; fi < 8; ++fi) {
        const int row = rowbase + fi * 16 + lhi * 4;
        float v[4];
#pragma unroll
        for (int r = 0; r < 4; ++r) v[r] = acc[fi][fj][r] + bj;
        const int bV = row >> 11, tt = row & 2047;
        const size_t base = ((size_t)((bV * NH + hV) * 32 + (tt >> 6))) * 4096
                          + (dcol >> 4) * 1024 + ((tt >> 4) & 1) * 512
                          + (((tt >> 2) & 3) * 16 + (dcol & 15)) * 8 + ((tt >> 5) & 1) * 4;
        ushort4 o4;
        o4.x = bf16_bits(v[0]); o4.y = bf16_bits(v[1]);
        o4.z = bf16_bits(v[2]); o4.w = bf16_bits(v[3]);
        *(ushort4*)&vt2[base] = o4;
      }
    }
  } else {
    const int hK = ((by - 4) << 2) + wc;
#pragma unroll
    for (int fi = 0; fi < 8; ++fi) {
#pragma unroll
      for (int fj = 0; fj < 4; ++fj) {
        const int col = n0 + wc * 64 + fj * 16 + lq;
        const float bj = f ? ((const float*)bias)[col] : bf2f(((const unsigned short*)bias)[col]);
#pragma unroll
        for (int r = 0; r < 4; ++r) {
          const float v = acc[fi][fj][r] + bj;
          Cw[(lhi * 4 + r) * 72 + fj * 16 + lq] = bf16_bits(isq ? v * QSCALE : v);
        }
      }
      if (isq) {
#pragma unroll
        for (int p = 0; p < 2; ++p) {
          const int row_l = p * 8 + (lane >> 3), col_l = (lane & 7) * 8;
          const bf16x8 v8 = ld8(&Cw[row_l * 72 + col_l]);
          *(bf16x8*)&qb[(size_t)(rowbase + fi * 16 + row_l) * NC + n0 + wc * 64 + col_l] = v8;
        }
      } else {
        const int rowglob = rowbase + fi * 16;
        const int bK = rowglob >> 11, tt = rowglob & 2047;
        const size_t tb = ((size_t)((bK * NH + hK) * 32 + (tt >> 6))) * 4096
                        + ((tt >> 4) & 3) * 1024;
#pragma unroll
        for (int p = 0; p < 2; ++p) {
          const bf16x8 v8 = ld8(&Cw[(lane & 15) * 72 + p * 32 + (lane >> 4) * 8]);
          *(bf16x8*)&kf2[tb + p * 512 + lane * 8] = v8;
        }
      }
    }
  }
}

// ---------- output projection GEMM: 128x64 tile, 512 blocks (2 blocks/CU) ----------
__global__ __launch_bounds__(256) void gemm_out(const unsigned short* __restrict__ A,
                                                const unsigned short* __restrict__ Bt,
                                                const void* __restrict__ bias,
                                                void* __restrict__ Cout,
                                                const unsigned short* __restrict__ xdet) {
  __shared__ unsigned short As[128][64];
  __shared__ unsigned short Bs[64][64];
  const int f = wave_is_f32(xdet);
  const int m0 = blockIdx.x * 128, n0 = blockIdx.y * 64;
  const int tid = threadIdx.x, w = tid >> 6, lane = tid & 63;
  const int lrow = lane & 15, lhi = lane >> 4;
  const int wr = w >> 1, wc = w & 1;
  const int grow = lane >> 3;
  const int gc = (((lane & 7) ^ grow) * 8);
  const int rg = (lrow & 7);
  f32x4 acc[4][2] = {};
  for (int k0 = 0; k0 < NC; k0 += 64) {
    __syncthreads();
#pragma unroll
    for (int p = 0; p < 4; ++p) {
      const int r = w * 32 + p * 8;
      g2l16(&A[(size_t)(m0 + r + grow) * NC + k0 + gc], &As[r][0]);
    }
#pragma unroll
    for (int p = 0; p < 2; ++p) {
      const int r = w * 16 + p * 8;
      g2l16(&Bt[(size_t)(n0 + r + grow) * NC + k0 + gc], &Bs[r][0]);
    }
    __syncthreads();
    bf16x8 af[2][4], bfr[2][2];
#pragma unroll
    for (int kk = 0; kk < 2; ++kk) {
#pragma unroll
      for (int i = 0; i < 4; ++i)
        af[kk][i] = ld8(&As[wr * 64 + i * 16 + lrow][((kk * 4 + lhi) ^ rg) * 8]);
#pragma unroll
      for (int j = 0; j < 2; ++j)
        bfr[kk][j] = ld8(&Bs[wc * 32 + j * 16 + lrow][((kk * 4 + lhi) ^ rg) * 8]);
    }
#pragma unroll
    for (int kk = 0; kk < 2; ++kk)
#pragma unroll
      for (int i = 0; i < 4; ++i)
#pragma unroll
        for (int j = 0; j < 2; ++j)
          acc[i][j] = __builtin_amdgcn_mfma_f32_16x16x32_bf16(af[kk][i], bfr[kk][j], acc[i][j], 0, 0, 0);
  }
#pragma unroll
  for (int j = 0; j < 2; ++j) {
    const int col = n0 + wc * 32 + j * 16 + lrow;
    const float bj = f ? ((const float*)bias)[col] : bf2f(((const unsigned short*)bias)[col]);
#pragma unroll
    for (int i = 0; i < 4; ++i) {
      const int row = m0 + wr * 64 + i * 16 + lhi * 4;
#pragma unroll
      for (int r = 0; r < 4; ++r) {
        const float v = acc[i][j][r] + bj;
        const size_t idx = (size_t)(row + r) * NC + col;
        if (f) ((float*)Cout)[idx] = v;
        else ((unsigned short*)Cout)[idx] = bf16_bits(v);
      }
    }
  }
}

// ---------- flash attention: r18 + FINE-GRAINED K/V reload interleave in g3 ----------
// Same register footprint (single kR/vR sets; frozen rule). kR[j] reloads
// immediately after its last read (g3's j-th QK pair); vR[jd] after its last
// read (g3's jd-th PV pair). Oldest reloads gain ~6 MFMAs of extra cover and
// the 16 loads spread across the MFMA stream instead of issuing en-bloc.
__global__ __launch_bounds__(64) void flash_attn(const unsigned short* __restrict__ q,
                                                 const unsigned short* __restrict__ kf2,
                                                 const unsigned short* __restrict__ vt2,
                                                 unsigned short* __restrict__ y) {
  const int fid = blockIdx.x + (blockIdx.y << 5);
  const int swz = ((fid & 7) << 7) + (fid >> 3);  // bijective: 1024 % 8 == 0
  const int qt = swz & 31, bh = swz >> 5;
  const int b = bh >> 4, h = bh & 15;
  const int lane = threadIdx.x;
  const int lq = lane & 15, lhi = lane >> 4;

  bf16x8 qf0[2], qf1[2], qf2[2], qf3[2];
  {
    const unsigned short* qp = q + (size_t)(b * NT + qt * 64 + lq) * NC + h * ND + lhi * 8;
    qf0[0] = ld8(qp);                      qf0[1] = ld8(qp + 32);
    qf1[0] = ld8(qp + (size_t)16 * NC);    qf1[1] = ld8(qp + (size_t)16 * NC + 32);
    qf2[0] = ld8(qp + (size_t)32 * NC);    qf2[1] = ld8(qp + (size_t)32 * NC + 32);
    qf3[0] = ld8(qp + (size_t)48 * NC);    qf3[1] = ld8(qp + (size_t)48 * NC + 32);
  }
  f32x4 acc0[4] = {}, acc1[4] = {}, acc2[4] = {}, acc3[4] = {};
  float l0 = 0.f, l1 = 0.f, l2 = 0.f, l3 = 0.f;
  const unsigned short* kbase = kf2 + ((size_t)bh * 32) * 4096 + (size_t)lane * 8;
  const unsigned short* vbase = vt2 + ((size_t)bh * 32) * 4096 + (size_t)lane * 8;

  bf16x8 kR[4][2], vR[4][2];
#define KLOAD(kt_)                                                              \
  {                                                                             \
    _Pragma("unroll") for (int j = 0; j < 4; ++j)                               \
      _Pragma("unroll") for (int kk = 0; kk < 2; ++kk)                          \
        kR[j][kk] = ld8(kbase + (size_t)(kt_)*4096 + j * 1024 + kk * 512);      \
  }
#define VLOAD(kt_)                                                              \
  {                                                                             \
    _Pragma("unroll") for (int jd = 0; jd < 4; ++jd)                            \
      _Pragma("unroll") for (int jj = 0; jj < 2; ++jj)                          \
        vR[jd][jj] = ld8(vbase + (size_t)(kt_)*4096 + jd * 1024 + jj * 512);    \
  }
// QK -> exp2 -> cvtpk -> PV -> (row-sum sunk below PV)
#define GROUP(QF_, ACC_, L_)                                                      \
  {                                                                               \
    f32x4 s0 = {}, s1 = {}, s2 = {}, s3 = {};                                     \
    s0 = __builtin_amdgcn_mfma_f32_16x16x32_bf16(kR[0][0], QF_[0], s0, 0, 0, 0);  \
    s0 = __builtin_amdgcn_mfma_f32_16x16x32_bf16(kR[0][1], QF_[1], s0, 0, 0, 0);  \
    s1 = __builtin_amdgcn_mfma_f32_16x16x32_bf16(kR[1][0], QF_[0], s1, 0, 0, 0);  \
    s1 = __builtin_amdgcn_mfma_f32_16x16x32_bf16(kR[1][1], QF_[1], s1, 0, 0, 0);  \
    s2 = __builtin_amdgcn_mfma_f32_16x16x32_bf16(kR[2][0], QF_[0], s2, 0, 0, 0);  \
    s2 = __builtin_amdgcn_mfma_f32_16x16x32_bf16(kR[2][1], QF_[1], s2, 0, 0, 0);  \
    s3 = __builtin_amdgcn_mfma_f32_16x16x32_bf16(kR[3][0], QF_[0], s3, 0, 0, 0);  \
    s3 = __builtin_amdgcn_mfma_f32_16x16x32_bf16(kR[3][1], QF_[1], s3, 0, 0, 0);  \
    _Pragma("unroll") for (int r = 0; r < 4; ++r) {                               \
      s0[r] = vexp2(s0[r]); s1[r] = vexp2(s1[r]);                                 \
      s2[r] = vexp2(s2[r]); s3[r] = vexp2(s3[r]);                                 \
    }                                                                             \
    union U { unsigned int u[4]; bf16x8 v; };                                     \
    U p0, p1;                                                                     \
    p0.u[0] = cvtpk(s0[0], s0[1]); p0.u[1] = cvtpk(s0[2], s0[3]);                 \
    p0.u[2] = cvtpk(s2[0], s2[1]); p0.u[3] = cvtpk(s2[2], s2[3]);                 \
    p1.u[0] = cvtpk(s1[0], s1[1]); p1.u[1] = cvtpk(s1[2], s1[3]);                 \
    p1.u[2] = cvtpk(s3[0], s3[1]); p1.u[3] = cvtpk(s3[2], s3[3]);                 \
    __builtin_amdgcn_s_setprio(1);                                                \
    _Pragma("unroll") for (int jd = 0; jd < 4; ++jd) {                            \
      ACC_[jd] = __builtin_amdgcn_mfma_f32_16x16x32_bf16(vR[jd][0], p0.v, ACC_[jd], 0, 0, 0); \
      ACC_[jd] = __builtin_amdgcn_mfma_f32_16x16x32_bf16(vR[jd][1], p1.v, ACC_[jd], 0, 0, 0); \
    }                                                                             \
    __builtin_amdgcn_s_setprio(0);                                                \
    float rs = 0.f;                                                               \
    _Pragma("unroll") for (int r = 0; r < 4; ++r)                                 \
      rs += (s0[r] + s1[r]) + (s2[r] + s3[r]);                                    \
    rs += __shfl_xor(rs, 16); rs += __shfl_xor(rs, 32);                           \
    L_ += rs;                                                                     \
  }

  KLOAD(0);
  VLOAD(0);
  for (int kt = 0; kt < 32; ++kt) {
    GROUP(qf0, acc0, l0);
    GROUP(qf1, acc1, l1);
    GROUP(qf2, acc2, l2);
    // group 3 inlined with fine-grained reloads: kR[j] reloads right after its
    // j-th QK pair; vR[jd] reloads right after its jd-th PV pair.
    {
      const int ktn = (kt + 1) & 31;  // last-iter loads are dead but harmless
      const unsigned short* kb2 = kbase + (size_t)ktn * 4096;
      const unsigned short* vb2 = vbase + (size_t)ktn * 4096;
      f32x4 s0 = {}, s1 = {}, s2 = {}, s3 = {};
      s0 = __builtin_amdgcn_mfma_f32_16x16x32_bf16(kR[0][0], qf3[0], s0, 0, 0, 0);
      s0 = __builtin_amdgcn_mfma_f32_16x16x32_bf16(kR[0][1], qf3[1], s0, 0, 0, 0);
      kR[0][0] = ld8(kb2);       kR[0][1] = ld8(kb2 + 512);
      s1 = __builtin_amdgcn_mfma_f32_16x16x32_bf16(kR[1][0], qf3[0], s1, 0, 0, 0);
      s1 = __builtin_amdgcn_mfma_f32_16x16x32_bf16(kR[1][1], qf3[1], s1, 0, 0, 0);
      kR[1][0] = ld8(kb2 + 1024); kR[1][1] = ld8(kb2 + 1536);
      s2 = __builtin_amdgcn_mfma_f32_16x16x32_bf16(kR[2][0], qf3[0], s2, 0, 0, 0);
      s2 = __builtin_amdgcn_mfma_f32_16x16x32_bf16(kR[2][1], qf3[1], s2, 0, 0, 0);
      kR[2][0] = ld8(kb2 + 2048); kR[2][1] = ld8(kb2 + 2560);
      s3 = __builtin_amdgcn_mfma_f32_16x16x32_bf16(kR[3][0], qf3[0], s3, 0, 0, 0);
      s3 = __builtin_amdgcn_mfma_f32_16x16x32_bf16(kR[3][1], qf3[1], s3, 0, 0, 0);
      kR[3][0] = ld8(kb2 + 3072); kR[3][1] = ld8(kb2 + 3584);
#pragma unroll
      for (int r = 0; r < 4; ++r) {
        s0[r] = vexp2(s0[r]); s1[r] = vexp2(s1[r]);
        s2[r] = vexp2(s2[r]); s3[r] = vexp2(s3[r]);
      }
      union U { unsigned int u[4]; bf16x8 v; };
      U p0, p1;
      p0.u[0] = cvtpk(s0[0], s0[1]); p0.u[1] = cvtpk(s0[2], s0[3]);
      p0.u[2] = cvtpk(s2[0], s2[1]); p0.u[3] = cvtpk(s2[2], s2[3]);
      p1.u[0] = cvtpk(s1[0], s1[1]); p1.u[1] = cvtpk(s1[2], s1[3]);
      p1.u[2] = cvtpk(s3[0], s3[1]); p1.u[3] = cvtpk(s3[2], s3[3]);
      __builtin_amdgcn_s_setprio(1);
      acc3[0] = __builtin_amdgcn_mfma_f32_16x16x32_bf16(vR[0][0], p0.v, acc3[0], 0, 0, 0);
      acc3[0] = __builtin_amdgcn_mfma_f32_16x16x32_bf16(vR[0][1], p1.v, acc3[0], 0, 0, 0);
      vR[0][0] = ld8(vb2);        vR[0][1] = ld8(vb2 + 512);
      acc3[1] = __builtin_amdgcn_mfma_f32_16x16x32_bf16(vR[1][0], p0.v, acc3[1], 0, 0, 0);
      acc3[1] = __builtin_amdgcn_mfma_f32_16x16x32_bf16(vR[1][1], p1.v, acc3[1], 0, 0, 0);
      vR[1][0] = ld8(vb2 + 1024); vR[1][1] = ld8(vb2 + 1536);
      acc3[2] = __builtin_amdgcn_mfma_f32_16x16x32_bf16(vR[2][0], p0.v, acc3[2], 0, 0, 0);
      acc3[2] = __builtin_amdgcn_mfma_f32_16x16x32_bf16(vR[2][1], p1.v, acc3[2], 0, 0, 0);
      vR[2][0] = ld8(vb2 + 2048); vR[2][1] = ld8(vb2 + 2560);
      acc3[3] = __builtin_amdgcn_mfma_f32_16x16x32_bf16(vR[3][0], p0.v, acc3[3], 0, 0, 0);
      acc3[3] = __builtin_amdgcn_mfma_f32_16x16x32_bf16(vR[3][1], p1.v, acc3[3], 0, 0, 0);
      vR[3][0] = ld8(vb2 + 3072); vR[3][1] = ld8(vb2 + 3584);
      __builtin_amdgcn_s_setprio(0);
      float rs = 0.f;
#pragma unroll
      for (int r = 0; r < 4; ++r)
        rs += (s0[r] + s1[r]) + (s2[r] + s3[r]);
      rs += __shfl_xor(rs, 16); rs += __shfl_xor(rs, 32);
      l3 += rs;
    }
  }
#undef KLOAD
#undef VLOAD
#undef GROUP

  const float i0 = 1.f / l0, i1 = 1.f / l1, i2 = 1.f / l2, i3 = 1.f / l3;
  const size_t base0 = (size_t)(b * NT + qt * 64 + lq) * NC + h * ND + lhi * 4;
#pragma unroll
  for (int jd = 0; jd < 4; ++jd) {
    uint2 o;
    o.x = cvtpk(acc0[jd][0] * i0, acc0[jd][1] * i0);
    o.y = cvtpk(acc0[jd][2] * i0, acc0[jd][3] * i0);
    *(uint2*)&y[base0 + jd * 16] = o;
    o.x = cvtpk(acc1[jd][0] * i1, acc1[jd][1] * i1);
    o.y = cvtpk(acc1[jd][2] * i1, acc1[jd][3] * i1);
    *(uint2*)&y[base0 + (size_t)16 * NC + jd * 16] = o;
    o.x = cvtpk(acc2[jd][0] * i2, acc2[jd][1] * i2);
    o.y = cvtpk(acc2[jd][2] * i2, acc2[jd][3] * i2);
    *(uint2*)&y[base0 + (size_t)32 * NC + jd * 16] = o;
    o.x = cvtpk(acc3[jd][0] * i3, acc3[jd][1] * i3);
    o.y = cvtpk(acc3[jd][2] * i3, acc3[jd][3] * i3);
    *(uint2*)&y[base0 + (size_t)48 * NC + jd * 16] = o;
  }
}

extern "C" void kernel_launch(void* const* d_in, const int* in_sizes, int n_in,
                              void* d_out, int out_size, void* d_ws, size_t ws_size,
                              hipStream_t stream) {
  (void)in_sizes; (void)n_in; (void)out_size; (void)ws_size;
  char* ws = (char*)d_ws;
  unsigned short* xq_b  = (unsigned short*)(ws);
  unsigned short* xkv_b = (unsigned short*)(ws + ((size_t)8  << 20));
  unsigned short* Wqt   = (unsigned short*)(ws + ((size_t)16 << 20));
  unsigned short* Wkvt  = (unsigned short*)(ws + ((size_t)18 << 20));
  unsigned short* Wot   = (unsigned short*)(ws + ((size_t)22 << 20));
  unsigned short* qb    = (unsigned short*)(ws + ((size_t)24 << 20));
  unsigned short* kf2   = (unsigned short*)(ws + ((size_t)32 << 20));
  unsigned short* vt2   = (unsigned short*)(ws + ((size_t)48 << 20));
  unsigned short* yb    = (unsigned short*)(ws + ((size_t)56 << 20));
  const unsigned short* xdet = (const unsigned short*)d_in[0];

  static bool attr_set = false;
  if (!attr_set) {
    hipFuncSetAttribute((const void*)gemm_qkv256,
                        hipFuncAttributeMaxDynamicSharedMemorySize, 131072);
    attr_set = true;
  }

  prep<<<dim3(256, 32), 256, 0, stream>>>(d_in[0], d_in[1], d_in[2], d_in[4], d_in[6],
                                          xq_b, xkv_b, Wqt, Wkvt, Wot);
  gemm_qkv256<<<dim3(16, 12), 512, 131072, stream>>>((const unsigned short*)d_in[0],
                                                     (const unsigned short*)d_in[1],
                                                     xq_b, xkv_b, Wqt, Wkvt,
                                                     d_in[3], d_in[5], qb, kf2, vt2);
  flash_attn<<<dim3(32, 32), 64, 0, stream>>>(qb, kf2, vt2, yb);
  gemm_out<<<dim3(32, 16), 256, 0, stream>>>(yb, Wot, d_in[7], d_out, xdet);
}

// Round 20
// 118.665 us; speedup vs baseline: 1.0119x; 1.0119x over previous
//
#include <hip/hip_runtime.h>

#define NB 2
#define NT 2048
#define NC 1024
#define NH 16
#define ND 64
#define NC2 2048
// 1/sqrt(D) * log2(e): folded into q-GEMM epilogue; flash uses 2^s directly.
#define QSCALE (0.125f * 1.4426950408889634f)

typedef __attribute__((ext_vector_type(8))) __bf16 bf16x8;
typedef __attribute__((ext_vector_type(8))) unsigned short ushort8;
typedef __attribute__((ext_vector_type(4))) float f32x4;

__device__ __forceinline__ unsigned short bf16_bits(float f) {
  union { float f; unsigned int u; } x; x.f = f;
  unsigned int r = x.u + 0x7fffu + ((x.u >> 16) & 1u);
  return (unsigned short)(r >> 16);
}
__device__ __forceinline__ float bf2f(unsigned short u) {
  union { unsigned int u; float f; } x; x.u = ((unsigned int)u) << 16;
  return x.f;
}
__device__ __forceinline__ void g2l16(const void* g, void* l) {
  __builtin_amdgcn_global_load_lds(
      (const __attribute__((address_space(1))) unsigned int*)g,
      (__attribute__((address_space(3))) unsigned int*)l, 16, 0, 0);
}
__device__ __forceinline__ bf16x8 ld8(const unsigned short* p) {
  return *(const bf16x8*)p;
}
__device__ __forceinline__ unsigned int cvtpk(float lo, float hi) {
  unsigned int r;
  asm("v_cvt_pk_bf16_f32 %0, %1, %2" : "=v"(r) : "v"(lo), "v"(hi));
  return r;
}
__device__ __forceinline__ float vexp2(float x) {  // 2^x
  float r;
  asm("v_exp_f32 %0, %1" : "=v"(r) : "v"(x));
  return r;
}

// ---------- per-wave dtype self-detect: 1 if d_in[0] holds f32, 0 if bf16 ----
__device__ __forceinline__ int wave_is_f32(const unsigned short* __restrict__ x) {
  const int lane = threadIdx.x & 63;
  ulonglong2 v = ((const ulonglong2*)x)[lane];
  const unsigned short* u = (const unsigned short*)&v;
  int c = 0;
#pragma unroll
  for (int k = 0; k < 8; ++k) {
    int e = (u[k] >> 7) & 0xFF;
    c += (e != 0 && (e < 112 || e > 142)) ? 1 : 0;
  }
#pragma unroll
  for (int off = 32; off > 0; off >>= 1) c += __shfl_down(c, off);
  return __shfl(c, 0) > 64;
}

// ---------- fused prep: activation convert (f32 only) + weight transpose ----------
__global__ __launch_bounds__(256) void prep(const void* __restrict__ xq,
                                            const void* __restrict__ xkv,
                                            const void* __restrict__ w0,
                                            const void* __restrict__ w1,
                                            const void* __restrict__ w2,
                                            unsigned short* __restrict__ oq,
                                            unsigned short* __restrict__ okv,
                                            unsigned short* __restrict__ o0,
                                            unsigned short* __restrict__ o1,
                                            unsigned short* __restrict__ o2) {
  __shared__ unsigned short tile[32][33];
  const int bx = blockIdx.x, by = blockIdx.y;
  const int f = wave_is_f32((const unsigned short*)xq);
  if (bx < 128) {
    if (!f) return;  // bf16: consumers read d_in directly; no copy needed
    const int fb = bx * 32 + by;  // [0, 4096)
    const void* in = (fb < 2048) ? xq : xkv;
    unsigned short* out = (fb < 2048) ? oq : okv;
    const int i = (fb & 2047) * 256 + threadIdx.x;
    const float4* p = (const float4*)in;
    float4 a = p[i * 2], b = p[i * 2 + 1];
    ushort8 o;
    o[0] = bf16_bits(a.x); o[1] = bf16_bits(a.y); o[2] = bf16_bits(a.z); o[3] = bf16_bits(a.w);
    o[4] = bf16_bits(b.x); o[5] = bf16_bits(b.y); o[6] = bf16_bits(b.z); o[7] = bf16_bits(b.w);
    *(ushort8*)&out[(size_t)i * 8] = o;
  } else {
    const int tb = bx - 128;
    const void* in; unsigned short* out; int cols, cb;
    if (tb < 32)      { in = w0; out = o0; cols = NC;  cb = tb; }
    else if (tb < 96) { in = w1; out = o1; cols = NC2; cb = tb - 32; }
    else              { in = w2; out = o2; cols = NC;  cb = tb - 96; }
    const int c0 = cb * 32, r0 = by * 32;  // rows = NC for all
    const int tx = threadIdx.x & 31, ty = threadIdx.x >> 5;
#pragma unroll
    for (int i = 0; i < 32; i += 8) {
      size_t idx = (size_t)(r0 + ty + i) * cols + c0 + tx;
      tile[ty + i][tx] = f ? bf16_bits(((const float*)in)[idx]) : ((const unsigned short*)in)[idx];
    }
    __syncthreads();
#pragma unroll
    for (int i = 0; i < 32; i += 8)
      out[(size_t)(c0 + ty + i) * NC + r0 + tx] = tile[tx][ty + i];
  }
}

// ---------- qkv projection GEMM: 256x256 tile, 8 waves, 4-phase pipelined ----------
// (r15-verified: T2 st_16x32 swizzle + 4-phase interleave + counted tile-end
// drain + setprio; panels by: 0-3 q, 4-7 K frag-major, 8-11 V frag-major.)
__global__ __launch_bounds__(512) void gemm_qkv256(const unsigned short* __restrict__ xq_raw,
                                                   const unsigned short* __restrict__ xkv_raw,
                                                   const unsigned short* __restrict__ xq_cvt,
                                                   const unsigned short* __restrict__ xkv_cvt,
                                                   const unsigned short* __restrict__ Wqt,
                                                   const unsigned short* __restrict__ Wkvt,
                                                   const void* __restrict__ bq,
                                                   const void* __restrict__ bkv,
                                                   unsigned short* __restrict__ qb,
                                                   unsigned short* __restrict__ kf2,
                                                   unsigned short* __restrict__ vt2) {
  extern __shared__ char smem[];  // 131072 B
  const int f = wave_is_f32(xq_raw);
  const int bx = blockIdx.x, by = blockIdx.y;
  const bool isq = by < 4;
  const unsigned short* A  = isq ? (f ? xq_cvt : xq_raw) : (f ? xkv_cvt : xkv_raw);
  const unsigned short* Bt = isq ? Wqt : Wkvt;
  const int m0 = bx * 256;
  const int n0 = (isq ? by : by - 4) * 256;
  const int tid = threadIdx.x, w = tid >> 6, lane = tid & 63;
  const int lq = lane & 15, lhi = lane >> 4;
  const int wr = w >> 2, wc = w & 3;
  f32x4 acc[8][4] = {};

#define STAGE_HALF(kt_, bf_, sel_)                                                   \
  {                                                                                  \
    const unsigned short* G_ = ((sel_) < 2) ? A : Bt;                                \
    const int r0_ = ((sel_) < 2) ? m0 : n0;                                          \
    const int h_ = (sel_) & 1;                                                       \
    char* db_ = smem + (bf_)*65536 + ((sel_) >> 1) * 32768 + h_ * 16384;             \
    _Pragma("unroll") for (int q_ = 0; q_ < 2; ++q_) {                               \
      const int o_ = w * 1024 + lane * 16 + q_ * 8192;                               \
      const int os_ = o_ ^ (((o_ >> 9) & 1) << 5);                                   \
      g2l16((const char*)G_ +                                                        \
                ((size_t)(r0_ + h_ * 128 + (os_ >> 7)) * NC + (kt_)*64) * 2 +        \
                (os_ & 127),                                                         \
            db_ + w * 1024 + q_ * 8192);                                             \
    }                                                                                \
  }

  STAGE_HALF(0, 0, 0);
  STAGE_HALF(0, 0, 1);
  STAGE_HALF(0, 0, 2);
  STAGE_HALF(0, 0, 3);
  asm volatile("s_waitcnt vmcnt(0)");
  __builtin_amdgcn_sched_barrier(0);
  __builtin_amdgcn_s_barrier();

  for (int T = 0; T < 16; ++T) {
    const int c = T & 1;
    const char* Ah = smem + c * 65536 + wr * 16384;
    const char* Bh = smem + c * 65536 + 32768 + (wc >> 1) * 16384;
    const int brh = (wc & 1) * 64;
    bf16x8 bF[2][4];
#pragma unroll
    for (int ph = 0; ph < 4; ++ph) {
      if (ph == 0) {
#pragma unroll
        for (int kk = 0; kk < 2; ++kk)
#pragma unroll
          for (int fj = 0; fj < 4; ++fj) {
            const int rowh = brh + fj * 16 + lq;
            const int o = rowh * 128 + kk * 64 + lhi * 16;
            bF[kk][fj] = ld8((const unsigned short*)(Bh + (o ^ (((o >> 9) & 1) << 5))));
          }
      }
      bf16x8 aF[2][2];
#pragma unroll
      for (int kk = 0; kk < 2; ++kk)
#pragma unroll
        for (int ii = 0; ii < 2; ++ii) {
          const int rowh = (ph * 2 + ii) * 16 + lq;
          const int o = rowh * 128 + kk * 64 + lhi * 16;
          aF[kk][ii] = ld8((const unsigned short*)(Ah + (o ^ (((o >> 9) & 1) << 5))));
        }
      if (T < 15) STAGE_HALF(T + 1, c ^ 1, ph);
      __builtin_amdgcn_s_barrier();
      __builtin_amdgcn_s_setprio(1);
#pragma unroll
      for (int kk = 0; kk < 2; ++kk)
#pragma unroll
        for (int ii = 0; ii < 2; ++ii)
#pragma unroll
          for (int fj = 0; fj < 4; ++fj)
            acc[ph * 2 + ii][fj] =
                __builtin_amdgcn_mfma_f32_16x16x32_bf16(aF[kk][ii], bF[kk][fj],
                                                        acc[ph * 2 + ii][fj], 0, 0, 0);
      __builtin_amdgcn_s_setprio(0);
    }
    asm volatile("s_waitcnt vmcnt(0)");
    __builtin_amdgcn_sched_barrier(0);
    __builtin_amdgcn_s_barrier();
  }
#undef STAGE_HALF

  // ---- epilogue (buffers all consumed; reuse smem for wave-private relayout) ----
  const void* bias = isq ? bq : bkv;
  const int rowbase = m0 + wr * 128;
  unsigned short* Cw = (unsigned short*)(smem + w * 2304);  // 16x72 elems per wave
  if (by >= 8) {
    const int n0v = (by - 8) * 256;
#pragma unroll
    for (int fj = 0; fj < 4; ++fj) {
      const int cv = n0v + wc * 64 + fj * 16 + lq;
      const float bj = f ? ((const float*)bias)[NC + cv]
                         : bf2f(((const unsigned short*)bias)[NC + cv]);
      const int hV = cv >> 6, dcol = cv & 63;
#pragma unroll
      for (int fi = 0; fi < 8; ++fi) {
        const int row = rowbase + fi * 16 + lhi * 4;
        float v[4];
#pragma unroll
        for (int r = 0; r < 4; ++r) v[r] = acc[fi][fj][r] + bj;
        const int bV = row >> 11, tt = row & 2047;
        const size_t base = ((size_t)((bV * NH + hV) * 32 + (tt >> 6))) * 4096
                          + (dcol >> 4) * 1024 + ((tt >> 4) & 1) * 512
                          + (((tt >> 2) & 3) * 16 + (dcol & 15)) * 8 + ((tt >> 5) & 1) * 4;
        ushort4 o4;
        o4.x = bf16_bits(v[0]); o4.y = bf16_bits(v[1]);
        o4.z = bf16_bits(v[2]); o4.w = bf16_bits(v[3]);
        *(ushort4*)&vt2[base] = o4;
      }
    }
  } else {
    const int hK = ((by - 4) << 2) + wc;
#pragma unroll
    for (int fi = 0; fi < 8; ++fi) {
#pragma unroll
      for (int fj = 0; fj < 4; ++fj) {
        const int col = n0 + wc * 64 + fj * 16 + lq;
        const float bj = f ? ((const float*)bias)[col] : bf2f(((const unsigned short*)bias)[col]);
#pragma unroll
        for (int r = 0; r < 4; ++r) {
          const float v = acc[fi][fj][r] + bj;
          Cw[(lhi * 4 + r) * 72 + fj * 16 + lq] = bf16_bits(isq ? v * QSCALE : v);
        }
      }
      if (isq) {
#pragma unroll
        for (int p = 0; p < 2; ++p) {
          const int row_l = p * 8 + (lane >> 3), col_l = (lane & 7) * 8;
          const bf16x8 v8 = ld8(&Cw[row_l * 72 + col_l]);
          *(bf16x8*)&qb[(size_t)(rowbase + fi * 16 + row_l) * NC + n0 + wc * 64 + col_l] = v8;
        }
      } else {
        const int rowglob = rowbase + fi * 16;
        const int bK = rowglob >> 11, tt = rowglob & 2047;
        const size_t tb = ((size_t)((bK * NH + hK) * 32 + (tt >> 6))) * 4096
                        + ((tt >> 4) & 3) * 1024;
#pragma unroll
        for (int p = 0; p < 2; ++p) {
          const bf16x8 v8 = ld8(&Cw[(lane & 15) * 72 + p * 32 + (lane >> 4) * 8]);
          *(bf16x8*)&kf2[tb + p * 512 + lane * 8] = v8;
        }
      }
    }
  }
}

// ---------- output projection GEMM: 128x64 tile, 512 blocks (2 blocks/CU) ----------
__global__ __launch_bounds__(256) void gemm_out(const unsigned short* __restrict__ A,
                                                const unsigned short* __restrict__ Bt,
                                                const void* __restrict__ bias,
                                                void* __restrict__ Cout,
                                                const unsigned short* __restrict__ xdet) {
  __shared__ unsigned short As[128][64];
  __shared__ unsigned short Bs[64][64];
  const int f = wave_is_f32(xdet);
  const int m0 = blockIdx.x * 128, n0 = blockIdx.y * 64;
  const int tid = threadIdx.x, w = tid >> 6, lane = tid & 63;
  const int lrow = lane & 15, lhi = lane >> 4;
  const int wr = w >> 1, wc = w & 1;
  const int grow = lane >> 3;
  const int gc = (((lane & 7) ^ grow) * 8);
  const int rg = (lrow & 7);
  f32x4 acc[4][2] = {};
  for (int k0 = 0; k0 < NC; k0 += 64) {
    __syncthreads();
#pragma unroll
    for (int p = 0; p < 4; ++p) {
      const int r = w * 32 + p * 8;
      g2l16(&A[(size_t)(m0 + r + grow) * NC + k0 + gc], &As[r][0]);
    }
#pragma unroll
    for (int p = 0; p < 2; ++p) {
      const int r = w * 16 + p * 8;
      g2l16(&Bt[(size_t)(n0 + r + grow) * NC + k0 + gc], &Bs[r][0]);
    }
    __syncthreads();
    bf16x8 af[2][4], bfr[2][2];
#pragma unroll
    for (int kk = 0; kk < 2; ++kk) {
#pragma unroll
      for (int i = 0; i < 4; ++i)
        af[kk][i] = ld8(&As[wr * 64 + i * 16 + lrow][((kk * 4 + lhi) ^ rg) * 8]);
#pragma unroll
      for (int j = 0; j < 2; ++j)
        bfr[kk][j] = ld8(&Bs[wc * 32 + j * 16 + lrow][((kk * 4 + lhi) ^ rg) * 8]);
    }
#pragma unroll
    for (int kk = 0; kk < 2; ++kk)
#pragma unroll
      for (int i = 0; i < 4; ++i)
#pragma unroll
        for (int j = 0; j < 2; ++j)
          acc[i][j] = __builtin_amdgcn_mfma_f32_16x16x32_bf16(af[kk][i], bfr[kk][j], acc[i][j], 0, 0, 0);
  }
#pragma unroll
  for (int j = 0; j < 2; ++j) {
    const int col = n0 + wc * 32 + j * 16 + lrow;
    const float bj = f ? ((const float*)bias)[col] : bf2f(((const unsigned short*)bias)[col]);
#pragma unroll
    for (int i = 0; i < 4; ++i) {
      const int row = m0 + wr * 64 + i * 16 + lhi * 4;
#pragma unroll
      for (int r = 0; r < 4; ++r) {
        const float v = acc[i][j][r] + bj;
        const size_t idx = (size_t)(row + r) * NC + col;
        if (f) ((float*)Cout)[idx] = v;
        else ((unsigned short*)Cout)[idx] = bf16_bits(v);
      }
    }
  }
}

// ---------- flash attention (round-18 verified version, byte-exact) ----------
// 1 wave/block, FOUR 16-row q-groups; single kR/vR register sets (en-bloc
// reload after last use — r19's fine-grained interleave regressed); row-sum
// sunk below PV. FROZEN: register growth NaN'd 3x (r5/r6/r16); the 55us level
// is dependency-structural for this kernel family.
__global__ __launch_bounds__(64) void flash_attn(const unsigned short* __restrict__ q,
                                                 const unsigned short* __restrict__ kf2,
                                                 const unsigned short* __restrict__ vt2,
                                                 unsigned short* __restrict__ y) {
  const int fid = blockIdx.x + (blockIdx.y << 5);
  const int swz = ((fid & 7) << 7) + (fid >> 3);  // bijective: 1024 % 8 == 0
  const int qt = swz & 31, bh = swz >> 5;
  const int b = bh >> 4, h = bh & 15;
  const int lane = threadIdx.x;
  const int lq = lane & 15, lhi = lane >> 4;

  bf16x8 qf0[2], qf1[2], qf2[2], qf3[2];
  {
    const unsigned short* qp = q + (size_t)(b * NT + qt * 64 + lq) * NC + h * ND + lhi * 8;
    qf0[0] = ld8(qp);                      qf0[1] = ld8(qp + 32);
    qf1[0] = ld8(qp + (size_t)16 * NC);    qf1[1] = ld8(qp + (size_t)16 * NC + 32);
    qf2[0] = ld8(qp + (size_t)32 * NC);    qf2[1] = ld8(qp + (size_t)32 * NC + 32);
    qf3[0] = ld8(qp + (size_t)48 * NC);    qf3[1] = ld8(qp + (size_t)48 * NC + 32);
  }
  f32x4 acc0[4] = {}, acc1[4] = {}, acc2[4] = {}, acc3[4] = {};
  float l0 = 0.f, l1 = 0.f, l2 = 0.f, l3 = 0.f;
  const unsigned short* kbase = kf2 + ((size_t)bh * 32) * 4096 + (size_t)lane * 8;
  const unsigned short* vbase = vt2 + ((size_t)bh * 32) * 4096 + (size_t)lane * 8;

  bf16x8 kR[4][2], vR[4][2];
#define KLOAD(kt_)                                                              \
  {                                                                             \
    _Pragma("unroll") for (int j = 0; j < 4; ++j)                               \
      _Pragma("unroll") for (int kk = 0; kk < 2; ++kk)                          \
        kR[j][kk] = ld8(kbase + (size_t)(kt_)*4096 + j * 1024 + kk * 512);      \
  }
#define VLOAD(kt_)                                                              \
  {                                                                             \
    _Pragma("unroll") for (int jd = 0; jd < 4; ++jd)                            \
      _Pragma("unroll") for (int jj = 0; jj < 2; ++jj)                          \
        vR[jd][jj] = ld8(vbase + (size_t)(kt_)*4096 + jd * 1024 + jj * 512);    \
  }
// QK -> exp2 -> cvtpk -> PV -> (row-sum sunk below PV)
#define GROUP(QF_, ACC_, L_)                                                      \
  {                                                                               \
    f32x4 s0 = {}, s1 = {}, s2 = {}, s3 = {};                                     \
    s0 = __builtin_amdgcn_mfma_f32_16x16x32_bf16(kR[0][0], QF_[0], s0, 0, 0, 0);  \
    s0 = __builtin_amdgcn_mfma_f32_16x16x32_bf16(kR[0][1], QF_[1], s0, 0, 0, 0);  \
    s1 = __builtin_amdgcn_mfma_f32_16x16x32_bf16(kR[1][0], QF_[0], s1, 0, 0, 0);  \
    s1 = __builtin_amdgcn_mfma_f32_16x16x32_bf16(kR[1][1], QF_[1], s1, 0, 0, 0);  \
    s2 = __builtin_amdgcn_mfma_f32_16x16x32_bf16(kR[2][0], QF_[0], s2, 0, 0, 0);  \
    s2 = __builtin_amdgcn_mfma_f32_16x16x32_bf16(kR[2][1], QF_[1], s2, 0, 0, 0);  \
    s3 = __builtin_amdgcn_mfma_f32_16x16x32_bf16(kR[3][0], QF_[0], s3, 0, 0, 0);  \
    s3 = __builtin_amdgcn_mfma_f32_16x16x32_bf16(kR[3][1], QF_[1], s3, 0, 0, 0);  \
    _Pragma("unroll") for (int r = 0; r < 4; ++r) {                               \
      s0[r] = vexp2(s0[r]); s1[r] = vexp2(s1[r]);                                 \
      s2[r] = vexp2(s2[r]); s3[r] = vexp2(s3[r]);                                 \
    }                                                                             \
    union U { unsigned int u[4]; bf16x8 v; };                                     \
    U p0, p1;                                                                     \
    p0.u[0] = cvtpk(s0[0], s0[1]); p0.u[1] = cvtpk(s0[2], s0[3]);                 \
    p0.u[2] = cvtpk(s2[0], s2[1]); p0.u[3] = cvtpk(s2[2], s2[3]);                 \
    p1.u[0] = cvtpk(s1[0], s1[1]); p1.u[1] = cvtpk(s1[2], s1[3]);                 \
    p1.u[2] = cvtpk(s3[0], s3[1]); p1.u[3] = cvtpk(s3[2], s3[3]);                 \
    __builtin_amdgcn_s_setprio(1);                                                \
    _Pragma("unroll") for (int jd = 0; jd < 4; ++jd) {                            \
      ACC_[jd] = __builtin_amdgcn_mfma_f32_16x16x32_bf16(vR[jd][0], p0.v, ACC_[jd], 0, 0, 0); \
      ACC_[jd] = __builtin_amdgcn_mfma_f32_16x16x32_bf16(vR[jd][1], p1.v, ACC_[jd], 0, 0, 0); \
    }                                                                             \
    __builtin_amdgcn_s_setprio(0);                                                \
    float rs = 0.f;                                                               \
    _Pragma("unroll") for (int r = 0; r < 4; ++r)                                 \
      rs += (s0[r] + s1[r]) + (s2[r] + s3[r]);                                    \
    rs += __shfl_xor(rs, 16); rs += __shfl_xor(rs, 32);                           \
    L_ += rs;                                                                     \
  }

  KLOAD(0);
  VLOAD(0);
  for (int kt = 0; kt < 32; ++kt) {
    GROUP(qf0, acc0, l0);
    GROUP(qf1, acc1, l1);
    GROUP(qf2, acc2, l2);
    // group 3 inlined: KLOAD(kt+1) after its QK; VLOAD(kt+1) after its PV,
    // before the (sunk) row-sum.
    {
      f32x4 s0 = {}, s1 = {}, s2 = {}, s3 = {};
      s0 = __builtin_amdgcn_mfma_f32_16x16x32_bf16(kR[0][0], qf3[0], s0, 0, 0, 0);
      s0 = __builtin_amdgcn_mfma_f32_16x16x32_bf16(kR[0][1], qf3[1], s0, 0, 0, 0);
      s1 = __builtin_amdgcn_mfma_f32_16x16x32_bf16(kR[1][0], qf3[0], s1, 0, 0, 0);
      s1 = __builtin_amdgcn_mfma_f32_16x16x32_bf16(kR[1][1], qf3[1], s1, 0, 0, 0);
      s2 = __builtin_amdgcn_mfma_f32_16x16x32_bf16(kR[2][0], qf3[0], s2, 0, 0, 0);
      s2 = __builtin_amdgcn_mfma_f32_16x16x32_bf16(kR[2][1], qf3[1], s2, 0, 0, 0);
      s3 = __builtin_amdgcn_mfma_f32_16x16x32_bf16(kR[3][0], qf3[0], s3, 0, 0, 0);
      s3 = __builtin_amdgcn_mfma_f32_16x16x32_bf16(kR[3][1], qf3[1], s3, 0, 0, 0);
      if (kt + 1 < 32) KLOAD(kt + 1);
#pragma unroll
      for (int r = 0; r < 4; ++r) {
        s0[r] = vexp2(s0[r]); s1[r] = vexp2(s1[r]);
        s2[r] = vexp2(s2[r]); s3[r] = vexp2(s3[r]);
      }
      union U { unsigned int u[4]; bf16x8 v; };
      U p0, p1;
      p0.u[0] = cvtpk(s0[0], s0[1]); p0.u[1] = cvtpk(s0[2], s0[3]);
      p0.u[2] = cvtpk(s2[0], s2[1]); p0.u[3] = cvtpk(s2[2], s2[3]);
      p1.u[0] = cvtpk(s1[0], s1[1]); p1.u[1] = cvtpk(s1[2], s1[3]);
      p1.u[2] = cvtpk(s3[0], s3[1]); p1.u[3] = cvtpk(s3[2], s3[3]);
      __builtin_amdgcn_s_setprio(1);
#pragma unroll
      for (int jd = 0; jd < 4; ++jd) {
        acc3[jd] = __builtin_amdgcn_mfma_f32_16x16x32_bf16(vR[jd][0], p0.v, acc3[jd], 0, 0, 0);
        acc3[jd] = __builtin_amdgcn_mfma_f32_16x16x32_bf16(vR[jd][1], p1.v, acc3[jd], 0, 0, 0);
      }
      __builtin_amdgcn_s_setprio(0);
      if (kt + 1 < 32) VLOAD(kt + 1);
      float rs = 0.f;
#pragma unroll
      for (int r = 0; r < 4; ++r)
        rs += (s0[r] + s1[r]) + (s2[r] + s3[r]);
      rs += __shfl_xor(rs, 16); rs += __shfl_xor(rs, 32);
      l3 += rs;
    }
  }
#undef KLOAD
#undef VLOAD
#undef GROUP

  const float i0 = 1.f / l0, i1 = 1.f / l1, i2 = 1.f / l2, i3 = 1.f / l3;
  const size_t base0 = (size_t)(b * NT + qt * 64 + lq) * NC + h * ND + lhi * 4;
#pragma unroll
  for (int jd = 0; jd < 4; ++jd) {
    uint2 o;
    o.x = cvtpk(acc0[jd][0] * i0, acc0[jd][1] * i0);
    o.y = cvtpk(acc0[jd][2] * i0, acc0[jd][3] * i0);
    *(uint2*)&y[base0 + jd * 16] = o;
    o.x = cvtpk(acc1[jd][0] * i1, acc1[jd][1] * i1);
    o.y = cvtpk(acc1[jd][2] * i1, acc1[jd][3] * i1);
    *(uint2*)&y[base0 + (size_t)16 * NC + jd * 16] = o;
    o.x = cvtpk(acc2[jd][0] * i2, acc2[jd][1] * i2);
    o.y = cvtpk(acc2[jd][2] * i2, acc2[jd][3] * i2);
    *(uint2*)&y[base0 + (size_t)32 * NC + jd * 16] = o;
    o.x = cvtpk(acc3[jd][0] * i3, acc3[jd][1] * i3);
    o.y = cvtpk(acc3[jd][2] * i3, acc3[jd][3] * i3);
    *(uint2*)&y[base0 + (size_t)48 * NC + jd * 16] = o;
  }
}

extern "C" void kernel_launch(void* const* d_in, const int* in_sizes, int n_in,
                              void* d_out, int out_size, void* d_ws, size_t ws_size,
                              hipStream_t stream) {
  (void)in_sizes; (void)n_in; (void)out_size; (void)ws_size;
  char* ws = (char*)d_ws;
  unsigned short* xq_b  = (unsigned short*)(ws);
  unsigned short* xkv_b = (unsigned short*)(ws + ((size_t)8  << 20));
  unsigned short* Wqt   = (unsigned short*)(ws + ((size_t)16 << 20));
  unsigned short* Wkvt  = (unsigned short*)(ws + ((size_t)18 << 20));
  unsigned short* Wot   = (unsigned short*)(ws + ((size_t)22 << 20));
  unsigned short* qb    = (unsigned short*)(ws + ((size_t)24 << 20));
  unsigned short* kf2   = (unsigned short*)(ws + ((size_t)32 << 20));
  unsigned short* vt2   = (unsigned short*)(ws + ((size_t)48 << 20));
  unsigned short* yb    = (unsigned short*)(ws + ((size_t)56 << 20));
  const unsigned short* xdet = (const unsigned short*)d_in[0];

  static bool attr_set = false;
  if (!attr_set) {
    hipFuncSetAttribute((const void*)gemm_qkv256,
                        hipFuncAttributeMaxDynamicSharedMemorySize, 131072);
    attr_set = true;
  }

  prep<<<dim3(256, 32), 256, 0, stream>>>(d_in[0], d_in[1], d_in[2], d_in[4], d_in[6],
                                          xq_b, xkv_b, Wqt, Wkvt, Wot);
  gemm_qkv256<<<dim3(16, 12), 512, 131072, stream>>>((const unsigned short*)d_in[0],
                                                     (const unsigned short*)d_in[1],
                                                     xq_b, xkv_b, Wqt, Wkvt,
                                                     d_in[3], d_in[5], qb, kf2, vt2);
  flash_attn<<<dim3(32, 32), 64, 0, stream>>>(qb, kf2, vt2, yb);
  gemm_out<<<dim3(32, 16), 256, 0, stream>>>(yb, Wot, d_in[7], d_out, xdet);
}